// Round 14
// baseline (620.238 us; speedup 1.0000x reference)
//
#include <hip/hip_runtime.h>
#include <math.h>

// ---------------- static problem config ----------------
#define N_NODES   100000
#define N_GRAPHS  100
#define NPG       1000
#define N_EDGES   1600000
#define EPG       16000      // edges per graph
#define HID       16
#define HEADS     4
#define HD        64
#define OUT_DIM   10
#define BN_EPS    1e-5f
#define NEG_SLOPE 0.2f

#define LDA 68   // sA row stride: 16B-aligned (68*4=272), conflict-free reads

// ---------------- workspace layout (float elements) ----------------
static const size_t OFF_EWP   = 0;         // 4 planes [E]
static const size_t OFF_PEWS  = 7000000;   // 384 floats
static const size_t OFF_POOL  = 7100000;   // pooled [100][64] ; pooledF0 at +6400
static const size_t OFF_DENP  = 7200000;   // den_p [N,4]
static const size_t OFF_DEND  = 7600000;   // den_d [N,4]
static const size_t OFF_HL    = 8000000;   // hl bf16 [N][128] = [N][64] uints
static const size_t OFF_CAT   = 20800000;  // gat_cat bf16 [N][128] = [N][64] uints
static const size_t OFF_F0    = 33600000;  // [N][64] fp32
static const size_t OFF_F1    = 40000000;  // [N][64]  <- ewd planes alias (dead before F1 write)
static const size_t OFF_EWD   = 40000000;
static const size_t OFF_SPS   = 46400000;  // sps float2 [N][4]  (s_p, s_d)
static const size_t OFF_DPD   = 47200000;  // dpd float2 [N][4]  (d_p, d_d)
static const size_t OFF_STATS = 48000000;  // 128 floats
static const size_t OFF_CSR   = 48000128;  // ints
static const size_t OFF_SRT   = 48100144;  // ints

// ---------------- bf16 helpers (RNE pack, exact unpack) ----------------
__device__ inline unsigned bf_pack(float x, float y) {
    unsigned ux = __float_as_uint(x);
    unsigned uy = __float_as_uint(y);
    ux = (ux + 0x7FFFu + ((ux >> 16) & 1u)) >> 16;
    uy = ((uy + 0x7FFFu + ((uy >> 16) & 1u)) >> 16) << 16;
    return ux | uy;
}
__device__ inline float bf_lo(unsigned u) { return __uint_as_float(u << 16); }
__device__ inline float bf_hi(unsigned u) { return __uint_as_float(u & 0xFFFF0000u); }

// ---------------- per-graph counting sort of edges by dst ----------------
__global__ __launch_bounds__(1024) void sort_edges(const int* __restrict__ ei,
                                                   int* __restrict__ csr_off,
                                                   int* __restrict__ sorted_src) {
    __shared__ int hist[1024];
    __shared__ int scan[1024];
    const int g = blockIdx.x;
    const int t = threadIdx.x;
    const int* src = ei;
    const int* dst = ei + N_EDGES;
    const int e0 = g * EPG;
    const int nbase = g * NPG;

    hist[t] = 0;
    __syncthreads();
    for (int i = t; i < EPG; i += 1024) {
        int d = dst[e0 + i] - nbase;
        atomicAdd(&hist[d], 1);
    }
    __syncthreads();
    scan[t] = hist[t];
    __syncthreads();
    for (int off = 1; off < 1024; off <<= 1) {
        int v = (t >= off) ? scan[t - off] : 0;
        __syncthreads();
        scan[t] += v;
        __syncthreads();
    }
    int excl = scan[t] - hist[t];
    if (t < NPG) csr_off[nbase + t] = e0 + excl;
    if (g == 0 && t == 0) csr_off[N_NODES] = N_EDGES;
    __syncthreads();
    hist[t] = excl;
    __syncthreads();
    for (int i = t; i < EPG; i += 1024) {
        int s = src[e0 + i];
        int d = dst[e0 + i] - nbase;
        int slot = atomicAdd(&hist[d], 1);
        sorted_src[e0 + slot] = s;
    }
}

// ---------------- PE rank-2 collapse ----------------
__global__ void prep_pe(const float* __restrict__ peW, const float* __restrict__ peb,
                        const float* __restrict__ Wp, const float* __restrict__ Wd,
                        float* __restrict__ pe) {
    int t = threadIdx.x;
    if (t < 128) {
        int r = t >> 6, c = t & 63;
        float sp = 0.f, sd = 0.f;
        for (int m = 0; m < 16; ++m) {
            sp += peW[r * 16 + m] * Wp[(64 + m) * 64 + c];
            sd += peW[r * 16 + m] * Wd[(64 + m) * 64 + c];
        }
        pe[r * 64 + c] = sp;
        pe[192 + r * 64 + c] = sd;
    } else if (t < 192) {
        int c = t & 63;
        float sp = 0.f, sd = 0.f;
        for (int m = 0; m < 16; ++m) {
            sp += peb[m] * Wp[(64 + m) * 64 + c];
            sd += peb[m] * Wd[(64 + m) * 64 + c];
        }
        pe[128 + c] = sp;
        pe[320 + c] = sd;
    }
}

// ---------------- register-tiled dual GEMM (K=64) + fused attention-logit epilogue ----------------
// W read directly from global (L2-resident; staging removed -> LDS 17.4KB, 8 blocks/CU).
template <bool PE>
__global__ __launch_bounds__(256) void gemm_dual_rt(const float* __restrict__ A,
                                                    const float* __restrict__ Wp,
                                                    const float* __restrict__ Wd,
                                                    const float* __restrict__ pe,
                                                    const float* __restrict__ pas,
                                                    const float* __restrict__ pad_,
                                                    const float* __restrict__ das,
                                                    const float* __restrict__ dad,
                                                    unsigned* __restrict__ hl,
                                                    float2* __restrict__ sps,
                                                    float2* __restrict__ dpd) {
    __shared__ float sA[64 * LDA];
    const int t = threadIdx.x;
    const int tx = t & 15, ty = t >> 4;
    const int node0 = blockIdx.x * 64;
    const int c4 = tx * 4;

#pragma unroll
    for (int it = 0; it < 4; ++it) {
        int n = ty + it * 16;
        int gn = node0 + n; if (gn > N_NODES - 1) gn = N_NODES - 1;
        *reinterpret_cast<float4*>(&sA[n * LDA + c4]) =
            *reinterpret_cast<const float4*>(&A[(size_t)gn * 64 + c4]);
    }
    __syncthreads();

    float4 accp[4], accd[4];
#pragma unroll
    for (int j = 0; j < 4; ++j) { accp[j] = float4{0,0,0,0}; accd[j] = float4{0,0,0,0}; }

    for (int k = 0; k < 64; k += 4) {
        float4 wp0 = *reinterpret_cast<const float4*>(&Wp[(size_t)(k + 0) * 64 + c4]);
        float4 wp1 = *reinterpret_cast<const float4*>(&Wp[(size_t)(k + 1) * 64 + c4]);
        float4 wp2 = *reinterpret_cast<const float4*>(&Wp[(size_t)(k + 2) * 64 + c4]);
        float4 wp3 = *reinterpret_cast<const float4*>(&Wp[(size_t)(k + 3) * 64 + c4]);
        float4 wd0 = *reinterpret_cast<const float4*>(&Wd[(size_t)(k + 0) * 64 + c4]);
        float4 wd1 = *reinterpret_cast<const float4*>(&Wd[(size_t)(k + 1) * 64 + c4]);
        float4 wd2 = *reinterpret_cast<const float4*>(&Wd[(size_t)(k + 2) * 64 + c4]);
        float4 wd3 = *reinterpret_cast<const float4*>(&Wd[(size_t)(k + 3) * 64 + c4]);
#pragma unroll
        for (int j = 0; j < 4; ++j) {
            float4 a = *reinterpret_cast<const float4*>(&sA[(ty * 4 + j) * LDA + k]);
            accp[j].x = fmaf(a.x, wp0.x, fmaf(a.y, wp1.x, fmaf(a.z, wp2.x, fmaf(a.w, wp3.x, accp[j].x))));
            accp[j].y = fmaf(a.x, wp0.y, fmaf(a.y, wp1.y, fmaf(a.z, wp2.y, fmaf(a.w, wp3.y, accp[j].y))));
            accp[j].z = fmaf(a.x, wp0.z, fmaf(a.y, wp1.z, fmaf(a.z, wp2.z, fmaf(a.w, wp3.z, accp[j].z))));
            accp[j].w = fmaf(a.x, wp0.w, fmaf(a.y, wp1.w, fmaf(a.z, wp2.w, fmaf(a.w, wp3.w, accp[j].w))));
            accd[j].x = fmaf(a.x, wd0.x, fmaf(a.y, wd1.x, fmaf(a.z, wd2.x, fmaf(a.w, wd3.x, accd[j].x))));
            accd[j].y = fmaf(a.x, wd0.y, fmaf(a.y, wd1.y, fmaf(a.z, wd2.y, fmaf(a.w, wd3.y, accd[j].y))));
            accd[j].z = fmaf(a.x, wd0.z, fmaf(a.y, wd1.z, fmaf(a.z, wd2.z, fmaf(a.w, wd3.z, accd[j].z))));
            accd[j].w = fmaf(a.x, wd0.w, fmaf(a.y, wd1.w, fmaf(a.z, wd2.w, fmaf(a.w, wd3.w, accd[j].w))));
        }
    }

    if (PE) {
        float4 pp0 = *reinterpret_cast<const float4*>(&pe[c4]);
        float4 pp1 = *reinterpret_cast<const float4*>(&pe[64 + c4]);
        float4 ppb = *reinterpret_cast<const float4*>(&pe[128 + c4]);
        float4 pd0 = *reinterpret_cast<const float4*>(&pe[192 + c4]);
        float4 pd1 = *reinterpret_cast<const float4*>(&pe[256 + c4]);
        float4 pdb = *reinterpret_cast<const float4*>(&pe[320 + c4]);
#pragma unroll
        for (int j = 0; j < 4; ++j) {
            int node = node0 + ty * 4 + j;
            int r = node % NPG;
            float px = (float)(r >> 5) * (1.0f / 31.0f);
            float py = (float)(r & 31) * (1.0f / 31.0f);
            accp[j].x += px * pp0.x + py * pp1.x + ppb.x;
            accp[j].y += px * pp0.y + py * pp1.y + ppb.y;
            accp[j].z += px * pp0.z + py * pp1.z + ppb.z;
            accp[j].w += px * pp0.w + py * pp1.w + ppb.w;
            accd[j].x += px * pd0.x + py * pd1.x + pdb.x;
            accd[j].y += px * pd0.y + py * pd1.y + pdb.y;
            accd[j].z += px * pd0.z + py * pd1.z + pdb.z;
            accd[j].w += px * pd0.w + py * pd1.w + pdb.w;
        }
    }

    float4 pasv = *reinterpret_cast<const float4*>(&pas[c4]);
    float4 padv = *reinterpret_cast<const float4*>(&pad_[c4]);
    float4 dasv = *reinterpret_cast<const float4*>(&das[c4]);
    float4 dadv = *reinterpret_cast<const float4*>(&dad[c4]);
    const int h = tx >> 2;
    const int cu = tx * 2;   // uint index within 64-uint row
#pragma unroll
    for (int j = 0; j < 4; ++j) {
        const int node = node0 + ty * 4 + j;
        float vps = accp[j].x * pasv.x + accp[j].y * pasv.y + accp[j].z * pasv.z + accp[j].w * pasv.w;
        float vpd = accp[j].x * padv.x + accp[j].y * padv.y + accp[j].z * padv.z + accp[j].w * padv.w;
        float vds = accd[j].x * dasv.x + accd[j].y * dasv.y + accd[j].z * dasv.z + accd[j].w * dasv.w;
        float vdd = accd[j].x * dadv.x + accd[j].y * dadv.y + accd[j].z * dadv.z + accd[j].w * dadv.w;
        vps += __shfl_xor(vps, 1); vps += __shfl_xor(vps, 2);
        vpd += __shfl_xor(vpd, 1); vpd += __shfl_xor(vpd, 2);
        vds += __shfl_xor(vds, 1); vds += __shfl_xor(vds, 2);
        vdd += __shfl_xor(vdd, 1); vdd += __shfl_xor(vdd, 2);
        if (node < N_NODES) {
            uint2 up, ud;
            up.x = bf_pack(accp[j].x, accp[j].y); up.y = bf_pack(accp[j].z, accp[j].w);
            ud.x = bf_pack(accd[j].x, accd[j].y); ud.y = bf_pack(accd[j].z, accd[j].w);
            *reinterpret_cast<uint2*>(&hl[(size_t)node * 64 + cu])      = up;
            *reinterpret_cast<uint2*>(&hl[(size_t)node * 64 + 32 + cu]) = ud;
            if ((tx & 3) == 0) {
                sps[node * 4 + h] = float2{vps, vds};
                dpd[node * 4 + h] = float2{vpd, vdd};
            }
        }
    }
}

// ---------------- fused GEMM: out = bf16A[N,128] @ W[128,64] + b, + BN stats ----------------
// W read from global (L2-resident); LDS 19.5KB -> 8 blocks/CU.
__global__ __launch_bounds__(256) void gemm_rt_bf(const unsigned* __restrict__ A,
                                                  const float* __restrict__ W,
                                                  const float* __restrict__ bias,
                                                  float* __restrict__ out,
                                                  float* __restrict__ stats) {
    __shared__ float sA[64 * LDA];
    __shared__ float red[512];
    const int t = threadIdx.x;
    const int tx = t & 15, ty = t >> 4;
    const int node0 = blockIdx.x * 64;
    const int c4 = tx * 4;

    float4 acc[4];
#pragma unroll
    for (int j = 0; j < 4; ++j) acc[j] = float4{0,0,0,0};

    for (int kc = 0; kc < 128; kc += 64) {
        __syncthreads();
        {
            const int n = t >> 2;
            const int part = t & 3;
            int gn = node0 + n; if (gn > N_NODES - 1) gn = N_NODES - 1;
            const unsigned* ap = A + (size_t)gn * 64 + (kc >> 1) + part * 8;
            uint4 w0 = *reinterpret_cast<const uint4*>(ap);
            uint4 w1 = *reinterpret_cast<const uint4*>(ap + 4);
            float* dst = &sA[n * LDA + part * 16];
            *reinterpret_cast<float4*>(dst + 0)  = float4{bf_lo(w0.x), bf_hi(w0.x), bf_lo(w0.y), bf_hi(w0.y)};
            *reinterpret_cast<float4*>(dst + 4)  = float4{bf_lo(w0.z), bf_hi(w0.z), bf_lo(w0.w), bf_hi(w0.w)};
            *reinterpret_cast<float4*>(dst + 8)  = float4{bf_lo(w1.x), bf_hi(w1.x), bf_lo(w1.y), bf_hi(w1.y)};
            *reinterpret_cast<float4*>(dst + 12) = float4{bf_lo(w1.z), bf_hi(w1.z), bf_lo(w1.w), bf_hi(w1.w)};
        }
        __syncthreads();
        const float* Wk = W + (size_t)kc * 64;
        for (int k = 0; k < 64; k += 4) {
            float4 w0 = *reinterpret_cast<const float4*>(&Wk[(size_t)(k + 0) * 64 + c4]);
            float4 w1 = *reinterpret_cast<const float4*>(&Wk[(size_t)(k + 1) * 64 + c4]);
            float4 w2 = *reinterpret_cast<const float4*>(&Wk[(size_t)(k + 2) * 64 + c4]);
            float4 w3 = *reinterpret_cast<const float4*>(&Wk[(size_t)(k + 3) * 64 + c4]);
#pragma unroll
            for (int j = 0; j < 4; ++j) {
                float4 a = *reinterpret_cast<const float4*>(&sA[(ty * 4 + j) * LDA + k]);
                acc[j].x = fmaf(a.x, w0.x, fmaf(a.y, w1.x, fmaf(a.z, w2.x, fmaf(a.w, w3.x, acc[j].x))));
                acc[j].y = fmaf(a.x, w0.y, fmaf(a.y, w1.y, fmaf(a.z, w2.y, fmaf(a.w, w3.y, acc[j].y))));
                acc[j].z = fmaf(a.x, w0.z, fmaf(a.y, w1.z, fmaf(a.z, w2.z, fmaf(a.w, w3.z, acc[j].z))));
                acc[j].w = fmaf(a.x, w0.w, fmaf(a.y, w1.w, fmaf(a.z, w2.w, fmaf(a.w, w3.w, acc[j].w))));
            }
        }
    }

    float4 bc = *reinterpret_cast<const float4*>(&bias[c4]);
    float4 ls = float4{0,0,0,0}, lq = float4{0,0,0,0};
#pragma unroll
    for (int j = 0; j < 4; ++j) {
        const int node = node0 + ty * 4 + j;
        if (node < N_NODES) {
            float4 v;
            v.x = acc[j].x + bc.x; v.y = acc[j].y + bc.y;
            v.z = acc[j].z + bc.z; v.w = acc[j].w + bc.w;
            *reinterpret_cast<float4*>(&out[(size_t)node * 64 + c4]) = v;
            ls.x += v.x; ls.y += v.y; ls.z += v.z; ls.w += v.w;
            lq.x += v.x * v.x; lq.y += v.y * v.y; lq.z += v.z * v.z; lq.w += v.w * v.w;
        }
    }
#pragma unroll
    for (int m = 16; m <= 32; m <<= 1) {
        ls.x += __shfl_xor(ls.x, m); ls.y += __shfl_xor(ls.y, m);
        ls.z += __shfl_xor(ls.z, m); ls.w += __shfl_xor(ls.w, m);
        lq.x += __shfl_xor(lq.x, m); lq.y += __shfl_xor(lq.y, m);
        lq.z += __shfl_xor(lq.z, m); lq.w += __shfl_xor(lq.w, m);
    }
    if ((t & 0x30) == 0) {
        int w = t >> 6;
        red[w * 64 + c4 + 0] = ls.x; red[w * 64 + c4 + 1] = ls.y;
        red[w * 64 + c4 + 2] = ls.z; red[w * 64 + c4 + 3] = ls.w;
        red[256 + w * 64 + c4 + 0] = lq.x; red[256 + w * 64 + c4 + 1] = lq.y;
        red[256 + w * 64 + c4 + 2] = lq.z; red[256 + w * 64 + c4 + 3] = lq.w;
    }
    __syncthreads();
    if (t < 64) {
        float s  = red[t] + red[64 + t] + red[128 + t] + red[192 + t];
        float sq = red[256 + t] + red[320 + t] + red[384 + t] + red[448 + t];
        atomicAdd(&stats[t], s);
        atomicAdd(&stats[64 + t], sq);
    }
}

// ---------------- per-(edge,head) softmax weights -> per-head planes + denominators ----------------
__global__ __launch_bounds__(256) void edge_weights(const float2* __restrict__ sps,
                                                    const float2* __restrict__ dpd,
                                                    const int* __restrict__ csr_off,
                                                    const int* __restrict__ sorted_src,
                                                    const float* __restrict__ posW,
                                                    const float* __restrict__ posb,
                                                    float* __restrict__ ewp,
                                                    float* __restrict__ ewd,
                                                    float* __restrict__ den_p,
                                                    float* __restrict__ den_d) {
    int v = blockIdx.x * 4 + (threadIdx.x >> 6);
    if (v >= N_NODES) return;
    const int lane = threadIdx.x & 63;
    const int h = lane & 3;        // head
    const int j = lane >> 2;       // edge slot 0..15

    int r = v % NPG;
    const float px = (float)(r >> 5) * (1.0f / 31.0f);
    const float py = (float)(r & 31) * (1.0f / 31.0f);
    const float pw0 = posW[h], pw1 = posW[4 + h], pb = posb[h];
    const float2 dv = dpd[v * 4 + h];      // (d_p, d_d)

    float* __restrict__ pwp = ewp + (size_t)h * N_EDGES;
    float* __restrict__ pwd = ewd + (size_t)h * N_EDGES;

    const int beg = csr_off[v];
    const int end = csr_off[v + 1];
    float psum = 0.f, dsum = 0.f;
    for (int e = beg + j; e < end; e += 16) {
        int src = sorted_src[e];
        int rs = src % NPG;
        float sx = (float)(rs >> 5) * (1.0f / 31.0f);
        float sy = (float)(rs & 31) * (1.0f / 31.0f);
        float extra = (px - sx) * pw0 + (py - sy) * pw1 + pb;
        float2 sv = sps[(size_t)src * 4 + h];   // (s_p, s_d) in one 8B load
        float ep = sv.x + dv.x + extra;
        float ed = sv.y + dv.y;
        ep = fmaxf(ep, NEG_SLOPE * ep);
        ed = fmaxf(ed, NEG_SLOPE * ed);
        float wp = __expf(ep);
        float wd = __expf(ed);
        pwp[e] = wp;
        pwd[e] = wd;
        psum += wp;
        dsum += wd;
    }
#pragma unroll
    for (int m = 4; m <= 32; m <<= 1) {
        psum += __shfl_xor(psum, m);
        dsum += __shfl_xor(dsum, m);
    }
    if (lane < 4) {                 // j==0, h==lane
        den_p[v * 4 + lane] = psum;
        den_d[v * 4 + lane] = dsum;
    }
}

// ---------------- dual-GAT aggregation: bf16 rows in, bf16 gat_cat out ----------------
__global__ __launch_bounds__(256) void gat_agg(const unsigned* __restrict__ hl,
                                               const float* __restrict__ ewp,
                                               const float* __restrict__ ewd,
                                               const float* __restrict__ den_p,
                                               const float* __restrict__ den_d,
                                               const int* __restrict__ csr_off,
                                               const int* __restrict__ sorted_src,
                                               unsigned* __restrict__ gat_cat) {
    const int b = blockIdx.x;
    const int logical = (b & 7) * 3125 + (b >> 3);   // XCD-aware swizzle
    const int v = logical * 4 + (threadIdx.x >> 6);
    if (v >= N_NODES) return;
    const int lane = threadIdx.x & 63;
    const int head = (lane & 31) >> 3;   // channel-pair group -> head

    const int beg = __builtin_amdgcn_readfirstlane(csr_off[v]);
    const int end = __builtin_amdgcn_readfirstlane(csr_off[v + 1]);

    const float* __restrict__ wplane = (lane >= 32 ? ewd : ewp) + (size_t)head * N_EDGES;

    float2 a0 = {0,0}, a1 = {0,0}, a2 = {0,0}, a3 = {0,0};
    int e = beg;
    for (; e + 8 <= end; e += 8) {
        int4 s4a = *reinterpret_cast<const int4*>(sorted_src + e);
        int4 s4b = *reinterpret_cast<const int4*>(sorted_src + e + 4);
        const unsigned* b0 = hl + ((size_t)(unsigned)__builtin_amdgcn_readfirstlane(s4a.x) << 6);
        const unsigned* b1 = hl + ((size_t)(unsigned)__builtin_amdgcn_readfirstlane(s4a.y) << 6);
        const unsigned* b2 = hl + ((size_t)(unsigned)__builtin_amdgcn_readfirstlane(s4a.z) << 6);
        const unsigned* b3 = hl + ((size_t)(unsigned)__builtin_amdgcn_readfirstlane(s4a.w) << 6);
        const unsigned* b4 = hl + ((size_t)(unsigned)__builtin_amdgcn_readfirstlane(s4b.x) << 6);
        const unsigned* b5 = hl + ((size_t)(unsigned)__builtin_amdgcn_readfirstlane(s4b.y) << 6);
        const unsigned* b6 = hl + ((size_t)(unsigned)__builtin_amdgcn_readfirstlane(s4b.z) << 6);
        const unsigned* b7 = hl + ((size_t)(unsigned)__builtin_amdgcn_readfirstlane(s4b.w) << 6);
        float4 wa = *reinterpret_cast<const float4*>(wplane + e);
        float4 wb = *reinterpret_cast<const float4*>(wplane + e + 4);
        unsigned u0 = b0[lane], u1 = b1[lane], u2 = b2[lane], u3 = b3[lane];
        unsigned u4 = b4[lane], u5 = b5[lane], u6 = b6[lane], u7 = b7[lane];
        a0.x = fmaf(wa.x, bf_lo(u0), a0.x); a0.y = fmaf(wa.x, bf_hi(u0), a0.y);
        a1.x = fmaf(wa.y, bf_lo(u1), a1.x); a1.y = fmaf(wa.y, bf_hi(u1), a1.y);
        a2.x = fmaf(wa.z, bf_lo(u2), a2.x); a2.y = fmaf(wa.z, bf_hi(u2), a2.y);
        a3.x = fmaf(wa.w, bf_lo(u3), a3.x); a3.y = fmaf(wa.w, bf_hi(u3), a3.y);
        a0.x = fmaf(wb.x, bf_lo(u4), a0.x); a0.y = fmaf(wb.x, bf_hi(u4), a0.y);
        a1.x = fmaf(wb.y, bf_lo(u5), a1.x); a1.y = fmaf(wb.y, bf_hi(u5), a1.y);
        a2.x = fmaf(wb.z, bf_lo(u6), a2.x); a2.y = fmaf(wb.z, bf_hi(u6), a2.y);
        a3.x = fmaf(wb.w, bf_lo(u7), a3.x); a3.y = fmaf(wb.w, bf_hi(u7), a3.y);
    }
    for (; e + 4 <= end; e += 4) {
        int4 s4 = *reinterpret_cast<const int4*>(sorted_src + e);
        const unsigned* b0 = hl + ((size_t)(unsigned)__builtin_amdgcn_readfirstlane(s4.x) << 6);
        const unsigned* b1 = hl + ((size_t)(unsigned)__builtin_amdgcn_readfirstlane(s4.y) << 6);
        const unsigned* b2 = hl + ((size_t)(unsigned)__builtin_amdgcn_readfirstlane(s4.z) << 6);
        const unsigned* b3 = hl + ((size_t)(unsigned)__builtin_amdgcn_readfirstlane(s4.w) << 6);
        float4 wa = *reinterpret_cast<const float4*>(wplane + e);
        unsigned u0 = b0[lane], u1 = b1[lane], u2 = b2[lane], u3 = b3[lane];
        a0.x = fmaf(wa.x, bf_lo(u0), a0.x); a0.y = fmaf(wa.x, bf_hi(u0), a0.y);
        a1.x = fmaf(wa.y, bf_lo(u1), a1.x); a1.y = fmaf(wa.y, bf_hi(u1), a1.y);
        a2.x = fmaf(wa.z, bf_lo(u2), a2.x); a2.y = fmaf(wa.z, bf_hi(u2), a2.y);
        a3.x = fmaf(wa.w, bf_lo(u3), a3.x); a3.y = fmaf(wa.w, bf_hi(u3), a3.y);
    }
    float2 acc = {(a0.x + a1.x) + (a2.x + a3.x), (a0.y + a1.y) + (a2.y + a3.y)};
    for (; e < end; ++e) {
        const unsigned* b0 = hl + ((size_t)(unsigned)__builtin_amdgcn_readfirstlane(sorted_src[e]) << 6);
        float wv = wplane[e];
        unsigned u0 = b0[lane];
        acc.x = fmaf(wv, bf_lo(u0), acc.x);
        acc.y = fmaf(wv, bf_hi(u0), acc.y);
    }
    const float den = (lane >= 32 ? den_d : den_p)[v * 4 + head] + 1e-16f;
    gat_cat[(size_t)v * 64 + lane] = bf_pack(acc.x / den, acc.y / den);
}

// ---------------- BN + ELU + fused graph pooling (optional F write-back) ----------------
template <bool WRITEF>
__global__ __launch_bounds__(256) void bn_elu(float* __restrict__ F, const float* __restrict__ stats,
                                              const float* __restrict__ gamma, const float* __restrict__ beta,
                                              float* __restrict__ pooled) {
    __shared__ float red[256];
    const int t = threadIdx.x;
    const int idx = blockIdx.x * 256 + t;
    const int c = t & 63;
    float mu = stats[c] * (1.0f / (float)N_NODES);
    float var = stats[64 + c] * (1.0f / (float)N_NODES) - mu * mu;
    float inv = rsqrtf(var + BN_EPS);
    float v = (F[idx] - mu) * inv * gamma[c] + beta[c];
    v = (v > 0.f) ? v : expm1f(v);
    if (WRITEF) F[idx] = v;
    red[t] = v;
    __syncthreads();
    if (t < 64) {
        float s = red[c] + red[64 + c] + red[128 + c] + red[192 + c];
        int g = (blockIdx.x * 4) / NPG;    // all 4 nodes in same graph
        atomicAdd(&pooled[g * 64 + c], s);
    }
}

// ---------------- task head: one wave per graph, residual folded in via pooled F0 ----------------
__global__ __launch_bounds__(64) void task_head(const float* __restrict__ pooled,
                                                const float* __restrict__ pooledF0,
                                                const float* __restrict__ resW,
                                                const float* __restrict__ resb,
                                                const float* __restrict__ taskW,
                                                const float* __restrict__ taskb,
                                                float* __restrict__ out) {
    const int g = blockIdx.x;
    const int c = threadIdx.x;
    float rc = 0.f;
    const float* pf = pooledF0 + g * 64;
    for (int k = 0; k < 64; ++k)
        rc = fmaf(pf[k], resW[k * 64 + c], rc);
    float p = (pooled[g * 64 + c] + rc) * (1.0f / (float)NPG) + resb[c];
#pragma unroll
    for (int o = 0; o < OUT_DIM; ++o) {
        float partial = p * taskW[c * OUT_DIM + o];
#pragma unroll
        for (int m = 1; m < 64; m <<= 1) partial += __shfl_xor(partial, m);
        if (c == 0) out[g * OUT_DIM + o] = partial + taskb[o];
    }
}

// ---------------- head-diversity loss for both layers ----------------
__global__ __launch_bounds__(256) void div_loss(const float* __restrict__ dW0,
                                                const float* __restrict__ dW1,
                                                float* __restrict__ out) {
    __shared__ float red[16][16];
    float total = 0.f;
    for (int layer = 0; layer < 2; ++layer) {
        const float* W = layer ? dW1 : dW0;
        const int din = layer ? 64 : 80;
        const int p = threadIdx.x & 15;
        const int s16 = threadIdx.x >> 4;
        const int i = p >> 2, j = p & 3;
        float acc = 0.f;
        const int Kk = din * 16;
        for (int kk = s16; kk < Kk; kk += 16) {
            int rrow = kk >> 4, cc = kk & 15;
            acc += W[rrow * 64 + i * 16 + cc] * W[rrow * 64 + j * 16 + cc];
        }
        red[p][s16] = acc;
        __syncthreads();
        if (threadIdx.x < 16) {
            float s = 0.f;
            for (int m = 0; m < 16; ++m) s += red[threadIdx.x][m];
            red[threadIdx.x][0] = s;
        }
        __syncthreads();
        if (threadIdx.x == 0) {
            float G[4][4], nrm[4];
            for (int a = 0; a < 4; ++a)
                for (int b = 0; b < 4; ++b) G[a][b] = red[a * 4 + b][0];
            for (int a = 0; a < 4; ++a) nrm[a] = sqrtf(G[a][a]) + 1e-12f;
            float l = 0.f;
            for (int a = 0; a < 4; ++a)
                for (int b = 0; b < 4; ++b) {
                    float gn = G[a][b] / (nrm[a] * nrm[b]);
                    float off = gn - (a == b ? 1.f : 0.f);
                    l += off * off;
                }
            total += 0.1f * l / 12.f;
        }
        __syncthreads();
    }
    if (threadIdx.x == 0) *out = total;
}

// ---------------- launcher ----------------
extern "C" void kernel_launch(void* const* d_in, const int* in_sizes, int n_in,
                              void* d_out, int out_size, void* d_ws, size_t ws_size,
                              hipStream_t stream) {
    const float* x      = (const float*)d_in[0];
    const int*   ei     = (const int*)d_in[1];
    const float* peW    = (const float*)d_in[3];
    const float* peb    = (const float*)d_in[4];

    const float* l_pW[2]   = {(const float*)d_in[5],  (const float*)d_in[17]};
    const float* l_pas[2]  = {(const float*)d_in[6],  (const float*)d_in[18]};
    const float* l_pad[2]  = {(const float*)d_in[7],  (const float*)d_in[19]};
    const float* l_posW[2] = {(const float*)d_in[8],  (const float*)d_in[20]};
    const float* l_posb[2] = {(const float*)d_in[9],  (const float*)d_in[21]};
    const float* l_dW[2]   = {(const float*)d_in[10], (const float*)d_in[22]};
    const float* l_das[2]  = {(const float*)d_in[11], (const float*)d_in[23]};
    const float* l_dad[2]  = {(const float*)d_in[12], (const float*)d_in[24]};
    const float* l_fW[2]   = {(const float*)d_in[13], (const float*)d_in[25]};
    const float* l_fb[2]   = {(const float*)d_in[14], (const float*)d_in[26]};
    const float* l_g[2]    = {(const float*)d_in[15], (const float*)d_in[27]};
    const float* l_b[2]    = {(const float*)d_in[16], (const float*)d_in[28]};
    const float* res_W  = (const float*)d_in[29];
    const float* res_b  = (const float*)d_in[30];
    const float* task_W = (const float*)d_in[31];
    const float* task_b = (const float*)d_in[32];

    float* ws = (float*)d_ws;
    float* ewp     = ws + OFF_EWP;
    float* pe_ws   = ws + OFF_PEWS;
    float* pooled  = ws + OFF_POOL;            // [100][64]
    float* pooledF0= ws + OFF_POOL + 6400;     // [100][64]
    float* den_p   = ws + OFF_DENP;
    float* den_d   = ws + OFF_DEND;
    unsigned* hl   = (unsigned*)(ws + OFF_HL);    // bf16 [N][128] = [N][64] uints
    unsigned* cat_bf = (unsigned*)(ws + OFF_CAT); // bf16 [N][128] = [N][64] uints
    float* F0      = ws + OFF_F0;
    float* F1      = ws + OFF_F1;
    float* ewd     = ws + OFF_EWD;   // aliases F1
    float2* sps    = (float2*)(ws + OFF_SPS);
    float2* dpd    = (float2*)(ws + OFF_DPD);
    float* stats   = ws + OFF_STATS;
    int*   csr_off    = (int*)(ws + OFF_CSR);
    int*   sorted_src = (int*)(ws + OFF_SRT);
    float* out = (float*)d_out;

    const int NODE_BLOCKS = (N_NODES + 3) / 4;      // 25000
    const int GEMM_BLOCKS = (N_NODES + 63) / 64;    // 1563
    const int BN_BLOCKS   = N_NODES * 64 / 256;     // 25000

    sort_edges<<<N_GRAPHS, 1024, 0, stream>>>(ei, csr_off, sorted_src);
    prep_pe<<<1, 256, 0, stream>>>(peW, peb, l_pW[0], l_dW[0], pe_ws);
    hipMemsetAsync(pooled, 0, 2 * N_GRAPHS * 64 * sizeof(float), stream);  // pooled + pooledF0

    // ----- layer 0 -----
    gemm_dual_rt<true><<<GEMM_BLOCKS, 256, 0, stream>>>(x, l_pW[0], l_dW[0], pe_ws,
        l_pas[0], l_pad[0], l_das[0], l_dad[0],
        hl, sps, dpd);
    edge_weights<<<NODE_BLOCKS, 256, 0, stream>>>(sps, dpd,
        csr_off, sorted_src, l_posW[0], l_posb[0], ewp, ewd, den_p, den_d);
    gat_agg<<<NODE_BLOCKS, 256, 0, stream>>>(hl, ewp, ewd, den_p, den_d,
        csr_off, sorted_src, cat_bf);
    hipMemsetAsync(stats, 0, 128 * sizeof(float), stream);
    gemm_rt_bf<<<GEMM_BLOCKS, 256, 0, stream>>>(cat_bf, l_fW[0], l_fb[0], F0, stats);
    bn_elu<true><<<BN_BLOCKS, 256, 0, stream>>>(F0, stats, l_g[0], l_b[0], pooledF0);

    // ----- layer 1 -----
    gemm_dual_rt<false><<<GEMM_BLOCKS, 256, 0, stream>>>(F0, l_pW[1], l_dW[1], pe_ws,
        l_pas[1], l_pad[1], l_das[1], l_dad[1],
        hl, sps, dpd);
    edge_weights<<<NODE_BLOCKS, 256, 0, stream>>>(sps, dpd,
        csr_off, sorted_src, l_posW[1], l_posb[1], ewp, ewd, den_p, den_d);
    gat_agg<<<NODE_BLOCKS, 256, 0, stream>>>(hl, ewp, ewd, den_p, den_d,
        csr_off, sorted_src, cat_bf);
    hipMemsetAsync(stats, 0, 128 * sizeof(float), stream);
    gemm_rt_bf<<<GEMM_BLOCKS, 256, 0, stream>>>(cat_bf, l_fW[1], l_fb[1], F1, stats);
    bn_elu<false><<<BN_BLOCKS, 256, 0, stream>>>(F1, stats, l_g[1], l_b[1], pooled);

    // ----- task head (residual folded via pooled F0) + diversity loss -----
    task_head<<<N_GRAPHS, 64, 0, stream>>>(pooled, pooledF0, res_W, res_b,
                                           task_W, task_b, out);
    div_loss<<<1, 256, 0, stream>>>(l_dW[0], l_dW[1], out + 1000);
}

// Round 17
// 571.683 us; speedup vs baseline: 1.0849x; 1.0849x over previous
//
#include <hip/hip_runtime.h>
#include <math.h>

// ---------------- static problem config ----------------
#define N_NODES   100000
#define N_GRAPHS  100
#define NPG       1000
#define N_EDGES   1600000
#define EPG       16000      // edges per graph
#define HID       16
#define HEADS     4
#define HD        64
#define OUT_DIM   10
#define BN_EPS    1e-5f
#define NEG_SLOPE 0.2f

#define LDA 68   // sA row stride: 16B-aligned (68*4=272), conflict-free reads

// ---------------- workspace layout (float elements) ----------------
static const size_t OFF_EWP   = 0;         // 4 planes [E]
static const size_t OFF_PEWS  = 7000000;   // 384 floats
static const size_t OFF_POOL  = 7100000;   // pooled [100][64] ; pooledF0 at +6400
static const size_t OFF_DENP  = 7200000;   // den_p [N,4]
static const size_t OFF_DEND  = 7600000;   // den_d [N,4]
static const size_t OFF_HL    = 8000000;   // hl bf16 [N][128] = [N][64] uints
static const size_t OFF_CAT   = 20800000;  // gat_cat bf16 [N][128] = [N][64] uints
static const size_t OFF_F0    = 33600000;  // [N][64] fp32
static const size_t OFF_F1    = 40000000;  // [N][64]  <- ewd planes alias (dead before F1 write)
static const size_t OFF_EWD   = 40000000;
static const size_t OFF_SPS   = 46400000;  // sps float2 [N][4]  (s_p, s_d)
static const size_t OFF_DPD   = 47200000;  // dpd float2 [N][4]  (d_p, d_d)
static const size_t OFF_STATS = 48000000;  // 128 floats
static const size_t OFF_CSR   = 48000128;  // ints
static const size_t OFF_SRT   = 48100144;  // ints

// ---------------- bf16 helpers (RNE pack, exact unpack) ----------------
__device__ inline unsigned bf_pack(float x, float y) {
    unsigned ux = __float_as_uint(x);
    unsigned uy = __float_as_uint(y);
    ux = (ux + 0x7FFFu + ((ux >> 16) & 1u)) >> 16;
    uy = ((uy + 0x7FFFu + ((uy >> 16) & 1u)) >> 16) << 16;
    return ux | uy;
}
__device__ inline float bf_lo(unsigned u) { return __uint_as_float(u << 16); }
__device__ inline float bf_hi(unsigned u) { return __uint_as_float(u & 0xFFFF0000u); }

// ---------------- per-graph counting sort of edges by dst ----------------
__global__ __launch_bounds__(1024) void sort_edges(const int* __restrict__ ei,
                                                   int* __restrict__ csr_off,
                                                   int* __restrict__ sorted_src) {
    __shared__ int hist[1024];
    __shared__ int scan[1024];
    const int g = blockIdx.x;
    const int t = threadIdx.x;
    const int* src = ei;
    const int* dst = ei + N_EDGES;
    const int e0 = g * EPG;
    const int nbase = g * NPG;

    hist[t] = 0;
    __syncthreads();
    for (int i = t; i < EPG; i += 1024) {
        int d = dst[e0 + i] - nbase;
        atomicAdd(&hist[d], 1);
    }
    __syncthreads();
    scan[t] = hist[t];
    __syncthreads();
    for (int off = 1; off < 1024; off <<= 1) {
        int v = (t >= off) ? scan[t - off] : 0;
        __syncthreads();
        scan[t] += v;
        __syncthreads();
    }
    int excl = scan[t] - hist[t];
    if (t < NPG) csr_off[nbase + t] = e0 + excl;
    if (g == 0 && t == 0) csr_off[N_NODES] = N_EDGES;
    __syncthreads();
    hist[t] = excl;
    __syncthreads();
    for (int i = t; i < EPG; i += 1024) {
        int s = src[e0 + i];
        int d = dst[e0 + i] - nbase;
        int slot = atomicAdd(&hist[d], 1);
        sorted_src[e0 + slot] = s;
    }
}

// ---------------- PE rank-2 collapse ----------------
__global__ void prep_pe(const float* __restrict__ peW, const float* __restrict__ peb,
                        const float* __restrict__ Wp, const float* __restrict__ Wd,
                        float* __restrict__ pe) {
    int t = threadIdx.x;
    if (t < 128) {
        int r = t >> 6, c = t & 63;
        float sp = 0.f, sd = 0.f;
        for (int m = 0; m < 16; ++m) {
            sp += peW[r * 16 + m] * Wp[(64 + m) * 64 + c];
            sd += peW[r * 16 + m] * Wd[(64 + m) * 64 + c];
        }
        pe[r * 64 + c] = sp;
        pe[192 + r * 64 + c] = sd;
    } else if (t < 192) {
        int c = t & 63;
        float sp = 0.f, sd = 0.f;
        for (int m = 0; m < 16; ++m) {
            sp += peb[m] * Wp[(64 + m) * 64 + c];
            sd += peb[m] * Wd[(64 + m) * 64 + c];
        }
        pe[128 + c] = sp;
        pe[320 + c] = sd;
    }
}

// ---------------- register-tiled dual GEMM (K=64) + fused attention-logit epilogue ----------------
// Staged W in LDS (load-bearing: converts per-iteration global latency into one barrier).
template <bool PE>
__global__ __launch_bounds__(256) void gemm_dual_rt(const float* __restrict__ A,
                                                    const float* __restrict__ Wp,
                                                    const float* __restrict__ Wd,
                                                    const float* __restrict__ pe,
                                                    const float* __restrict__ pas,
                                                    const float* __restrict__ pad_,
                                                    const float* __restrict__ das,
                                                    const float* __restrict__ dad,
                                                    unsigned* __restrict__ hl,
                                                    float2* __restrict__ sps,
                                                    float2* __restrict__ dpd) {
    __shared__ float sA[64 * LDA];
    __shared__ float sWp[64 * 64];
    __shared__ float sWd[64 * 64];
    const int t = threadIdx.x;
    const int tx = t & 15, ty = t >> 4;
    const int node0 = blockIdx.x * 64;
    const int c4 = tx * 4;

#pragma unroll
    for (int it = 0; it < 4; ++it) {
        int n = ty + it * 16;
        int gn = node0 + n; if (gn > N_NODES - 1) gn = N_NODES - 1;
        *reinterpret_cast<float4*>(&sA[n * LDA + c4]) =
            *reinterpret_cast<const float4*>(&A[(size_t)gn * 64 + c4]);
        *reinterpret_cast<float4*>(&sWp[n * 64 + c4]) =
            *reinterpret_cast<const float4*>(&Wp[(size_t)n * 64 + c4]);
        *reinterpret_cast<float4*>(&sWd[n * 64 + c4]) =
            *reinterpret_cast<const float4*>(&Wd[(size_t)n * 64 + c4]);
    }
    __syncthreads();

    float4 accp[4], accd[4];
#pragma unroll
    for (int j = 0; j < 4; ++j) { accp[j] = float4{0,0,0,0}; accd[j] = float4{0,0,0,0}; }

    for (int k = 0; k < 64; k += 4) {
        float4 wp0 = *reinterpret_cast<const float4*>(&sWp[(k + 0) * 64 + c4]);
        float4 wp1 = *reinterpret_cast<const float4*>(&sWp[(k + 1) * 64 + c4]);
        float4 wp2 = *reinterpret_cast<const float4*>(&sWp[(k + 2) * 64 + c4]);
        float4 wp3 = *reinterpret_cast<const float4*>(&sWp[(k + 3) * 64 + c4]);
        float4 wd0 = *reinterpret_cast<const float4*>(&sWd[(k + 0) * 64 + c4]);
        float4 wd1 = *reinterpret_cast<const float4*>(&sWd[(k + 1) * 64 + c4]);
        float4 wd2 = *reinterpret_cast<const float4*>(&sWd[(k + 2) * 64 + c4]);
        float4 wd3 = *reinterpret_cast<const float4*>(&sWd[(k + 3) * 64 + c4]);
#pragma unroll
        for (int j = 0; j < 4; ++j) {
            float4 a = *reinterpret_cast<const float4*>(&sA[(ty * 4 + j) * LDA + k]);
            accp[j].x = fmaf(a.x, wp0.x, fmaf(a.y, wp1.x, fmaf(a.z, wp2.x, fmaf(a.w, wp3.x, accp[j].x))));
            accp[j].y = fmaf(a.x, wp0.y, fmaf(a.y, wp1.y, fmaf(a.z, wp2.y, fmaf(a.w, wp3.y, accp[j].y))));
            accp[j].z = fmaf(a.x, wp0.z, fmaf(a.y, wp1.z, fmaf(a.z, wp2.z, fmaf(a.w, wp3.z, accp[j].z))));
            accp[j].w = fmaf(a.x, wp0.w, fmaf(a.y, wp1.w, fmaf(a.z, wp2.w, fmaf(a.w, wp3.w, accp[j].w))));
            accd[j].x = fmaf(a.x, wd0.x, fmaf(a.y, wd1.x, fmaf(a.z, wd2.x, fmaf(a.w, wd3.x, accd[j].x))));
            accd[j].y = fmaf(a.x, wd0.y, fmaf(a.y, wd1.y, fmaf(a.z, wd2.y, fmaf(a.w, wd3.y, accd[j].y))));
            accd[j].z = fmaf(a.x, wd0.z, fmaf(a.y, wd1.z, fmaf(a.z, wd2.z, fmaf(a.w, wd3.z, accd[j].z))));
            accd[j].w = fmaf(a.x, wd0.w, fmaf(a.y, wd1.w, fmaf(a.z, wd2.w, fmaf(a.w, wd3.w, accd[j].w))));
        }
    }

    if (PE) {
        float4 pp0 = *reinterpret_cast<const float4*>(&pe[c4]);
        float4 pp1 = *reinterpret_cast<const float4*>(&pe[64 + c4]);
        float4 ppb = *reinterpret_cast<const float4*>(&pe[128 + c4]);
        float4 pd0 = *reinterpret_cast<const float4*>(&pe[192 + c4]);
        float4 pd1 = *reinterpret_cast<const float4*>(&pe[256 + c4]);
        float4 pdb = *reinterpret_cast<const float4*>(&pe[320 + c4]);
#pragma unroll
        for (int j = 0; j < 4; ++j) {
            int node = node0 + ty * 4 + j;
            int r = node % NPG;
            float px = (float)(r >> 5) * (1.0f / 31.0f);
            float py = (float)(r & 31) * (1.0f / 31.0f);
            accp[j].x += px * pp0.x + py * pp1.x + ppb.x;
            accp[j].y += px * pp0.y + py * pp1.y + ppb.y;
            accp[j].z += px * pp0.z + py * pp1.z + ppb.z;
            accp[j].w += px * pp0.w + py * pp1.w + ppb.w;
            accd[j].x += px * pd0.x + py * pd1.x + pdb.x;
            accd[j].y += px * pd0.y + py * pd1.y + pdb.y;
            accd[j].z += px * pd0.z + py * pd1.z + pdb.z;
            accd[j].w += px * pd0.w + py * pd1.w + pdb.w;
        }
    }

    float4 pasv = *reinterpret_cast<const float4*>(&pas[c4]);
    float4 padv = *reinterpret_cast<const float4*>(&pad_[c4]);
    float4 dasv = *reinterpret_cast<const float4*>(&das[c4]);
    float4 dadv = *reinterpret_cast<const float4*>(&dad[c4]);
    const int h = tx >> 2;
    const int cu = tx * 2;   // uint index within 64-uint row
#pragma unroll
    for (int j = 0; j < 4; ++j) {
        const int node = node0 + ty * 4 + j;
        float vps = accp[j].x * pasv.x + accp[j].y * pasv.y + accp[j].z * pasv.z + accp[j].w * pasv.w;
        float vpd = accp[j].x * padv.x + accp[j].y * padv.y + accp[j].z * padv.z + accp[j].w * padv.w;
        float vds = accd[j].x * dasv.x + accd[j].y * dasv.y + accd[j].z * dasv.z + accd[j].w * dasv.w;
        float vdd = accd[j].x * dadv.x + accd[j].y * dadv.y + accd[j].z * dadv.z + accd[j].w * dadv.w;
        vps += __shfl_xor(vps, 1); vps += __shfl_xor(vps, 2);
        vpd += __shfl_xor(vpd, 1); vpd += __shfl_xor(vpd, 2);
        vds += __shfl_xor(vds, 1); vds += __shfl_xor(vds, 2);
        vdd += __shfl_xor(vdd, 1); vdd += __shfl_xor(vdd, 2);
        if (node < N_NODES) {
            uint2 up, ud;
            up.x = bf_pack(accp[j].x, accp[j].y); up.y = bf_pack(accp[j].z, accp[j].w);
            ud.x = bf_pack(accd[j].x, accd[j].y); ud.y = bf_pack(accd[j].z, accd[j].w);
            *reinterpret_cast<uint2*>(&hl[(size_t)node * 64 + cu])      = up;
            *reinterpret_cast<uint2*>(&hl[(size_t)node * 64 + 32 + cu]) = ud;
            if ((tx & 3) == 0) {
                sps[node * 4 + h] = float2{vps, vds};
                dpd[node * 4 + h] = float2{vpd, vdd};
            }
        }
    }
}

// ---------------- fused GEMM: out = bf16A[N,128] @ W[128,64] + b, + BN stats ----------------
__global__ __launch_bounds__(256) void gemm_rt_bf(const unsigned* __restrict__ A,
                                                  const float* __restrict__ W,
                                                  const float* __restrict__ bias,
                                                  float* __restrict__ out,
                                                  float* __restrict__ stats) {
    __shared__ float sA[64 * LDA];
    __shared__ float sW[64 * 64];
    __shared__ float red[512];
    const int t = threadIdx.x;
    const int tx = t & 15, ty = t >> 4;
    const int node0 = blockIdx.x * 64;
    const int c4 = tx * 4;

    float4 acc[4];
#pragma unroll
    for (int j = 0; j < 4; ++j) acc[j] = float4{0,0,0,0};

    for (int kc = 0; kc < 128; kc += 64) {
        __syncthreads();
        {
            const int n = t >> 2;
            const int part = t & 3;
            int gn = node0 + n; if (gn > N_NODES - 1) gn = N_NODES - 1;
            const unsigned* ap = A + (size_t)gn * 64 + (kc >> 1) + part * 8;
            uint4 w0 = *reinterpret_cast<const uint4*>(ap);
            uint4 w1 = *reinterpret_cast<const uint4*>(ap + 4);
            float* dst = &sA[n * LDA + part * 16];
            *reinterpret_cast<float4*>(dst + 0)  = float4{bf_lo(w0.x), bf_hi(w0.x), bf_lo(w0.y), bf_hi(w0.y)};
            *reinterpret_cast<float4*>(dst + 4)  = float4{bf_lo(w0.z), bf_hi(w0.z), bf_lo(w0.w), bf_hi(w0.w)};
            *reinterpret_cast<float4*>(dst + 8)  = float4{bf_lo(w1.x), bf_hi(w1.x), bf_lo(w1.y), bf_hi(w1.y)};
            *reinterpret_cast<float4*>(dst + 12) = float4{bf_lo(w1.z), bf_hi(w1.z), bf_lo(w1.w), bf_hi(w1.w)};
        }
#pragma unroll
        for (int it = 0; it < 4; ++it) {
            int n = ty + it * 16;
            *reinterpret_cast<float4*>(&sW[n * 64 + c4]) =
                *reinterpret_cast<const float4*>(&W[(size_t)(kc + n) * 64 + c4]);
        }
        __syncthreads();
        for (int k = 0; k < 64; k += 4) {
            float4 w0 = *reinterpret_cast<const float4*>(&sW[(k + 0) * 64 + c4]);
            float4 w1 = *reinterpret_cast<const float4*>(&sW[(k + 1) * 64 + c4]);
            float4 w2 = *reinterpret_cast<const float4*>(&sW[(k + 2) * 64 + c4]);
            float4 w3 = *reinterpret_cast<const float4*>(&sW[(k + 3) * 64 + c4]);
#pragma unroll
            for (int j = 0; j < 4; ++j) {
                float4 a = *reinterpret_cast<const float4*>(&sA[(ty * 4 + j) * LDA + k]);
                acc[j].x = fmaf(a.x, w0.x, fmaf(a.y, w1.x, fmaf(a.z, w2.x, fmaf(a.w, w3.x, acc[j].x))));
                acc[j].y = fmaf(a.x, w0.y, fmaf(a.y, w1.y, fmaf(a.z, w2.y, fmaf(a.w, w3.y, acc[j].y))));
                acc[j].z = fmaf(a.x, w0.z, fmaf(a.y, w1.z, fmaf(a.z, w2.z, fmaf(a.w, w3.z, acc[j].z))));
                acc[j].w = fmaf(a.x, w0.w, fmaf(a.y, w1.w, fmaf(a.z, w2.w, fmaf(a.w, w3.w, acc[j].w))));
            }
        }
    }

    float4 bc = *reinterpret_cast<const float4*>(&bias[c4]);
    float4 ls = float4{0,0,0,0}, lq = float4{0,0,0,0};
#pragma unroll
    for (int j = 0; j < 4; ++j) {
        const int node = node0 + ty * 4 + j;
        if (node < N_NODES) {
            float4 v;
            v.x = acc[j].x + bc.x; v.y = acc[j].y + bc.y;
            v.z = acc[j].z + bc.z; v.w = acc[j].w + bc.w;
            *reinterpret_cast<float4*>(&out[(size_t)node * 64 + c4]) = v;
            ls.x += v.x; ls.y += v.y; ls.z += v.z; ls.w += v.w;
            lq.x += v.x * v.x; lq.y += v.y * v.y; lq.z += v.z * v.z; lq.w += v.w * v.w;
        }
    }
#pragma unroll
    for (int m = 16; m <= 32; m <<= 1) {
        ls.x += __shfl_xor(ls.x, m); ls.y += __shfl_xor(ls.y, m);
        ls.z += __shfl_xor(ls.z, m); ls.w += __shfl_xor(ls.w, m);
        lq.x += __shfl_xor(lq.x, m); lq.y += __shfl_xor(lq.y, m);
        lq.z += __shfl_xor(lq.z, m); lq.w += __shfl_xor(lq.w, m);
    }
    if ((t & 0x30) == 0) {
        int w = t >> 6;
        red[w * 64 + c4 + 0] = ls.x; red[w * 64 + c4 + 1] = ls.y;
        red[w * 64 + c4 + 2] = ls.z; red[w * 64 + c4 + 3] = ls.w;
        red[256 + w * 64 + c4 + 0] = lq.x; red[256 + w * 64 + c4 + 1] = lq.y;
        red[256 + w * 64 + c4 + 2] = lq.z; red[256 + w * 64 + c4 + 3] = lq.w;
    }
    __syncthreads();
    if (t < 64) {
        float s  = red[t] + red[64 + t] + red[128 + t] + red[192 + t];
        float sq = red[256 + t] + red[320 + t] + red[384 + t] + red[448 + t];
        atomicAdd(&stats[t], s);
        atomicAdd(&stats[64 + t], sq);
    }
}

// ---------------- per-(edge,head) softmax weights -> per-head planes + denominators ----------------
__global__ __launch_bounds__(256) void edge_weights(const float2* __restrict__ sps,
                                                    const float2* __restrict__ dpd,
                                                    const int* __restrict__ csr_off,
                                                    const int* __restrict__ sorted_src,
                                                    const float* __restrict__ posW,
                                                    const float* __restrict__ posb,
                                                    float* __restrict__ ewp,
                                                    float* __restrict__ ewd,
                                                    float* __restrict__ den_p,
                                                    float* __restrict__ den_d) {
    int v = blockIdx.x * 4 + (threadIdx.x >> 6);
    if (v >= N_NODES) return;
    const int lane = threadIdx.x & 63;
    const int h = lane & 3;        // head
    const int j = lane >> 2;       // edge slot 0..15

    int r = v % NPG;
    const float px = (float)(r >> 5) * (1.0f / 31.0f);
    const float py = (float)(r & 31) * (1.0f / 31.0f);
    const float pw0 = posW[h], pw1 = posW[4 + h], pb = posb[h];
    const float2 dv = dpd[v * 4 + h];      // (d_p, d_d)

    float* __restrict__ pwp = ewp + (size_t)h * N_EDGES;
    float* __restrict__ pwd = ewd + (size_t)h * N_EDGES;

    const int beg = csr_off[v];
    const int end = csr_off[v + 1];
    float psum = 0.f, dsum = 0.f;
    for (int e = beg + j; e < end; e += 16) {
        int src = sorted_src[e];
        int rs = src % NPG;
        float sx = (float)(rs >> 5) * (1.0f / 31.0f);
        float sy = (float)(rs & 31) * (1.0f / 31.0f);
        float extra = (px - sx) * pw0 + (py - sy) * pw1 + pb;
        float2 sv = sps[(size_t)src * 4 + h];   // (s_p, s_d) in one 8B load
        float ep = sv.x + dv.x + extra;
        float ed = sv.y + dv.y;
        ep = fmaxf(ep, NEG_SLOPE * ep);
        ed = fmaxf(ed, NEG_SLOPE * ed);
        float wp = __expf(ep);
        float wd = __expf(ed);
        pwp[e] = wp;
        pwd[e] = wd;
        psum += wp;
        dsum += wd;
    }
#pragma unroll
    for (int m = 4; m <= 32; m <<= 1) {
        psum += __shfl_xor(psum, m);
        dsum += __shfl_xor(dsum, m);
    }
    if (lane < 4) {                 // j==0, h==lane
        den_p[v * 4 + lane] = psum;
        den_d[v * 4 + lane] = dsum;
    }
}

// ---------------- dual-GAT aggregation: bf16 rows in, bf16 gat_cat out ----------------
__global__ __launch_bounds__(256) void gat_agg(const unsigned* __restrict__ hl,
                                               const float* __restrict__ ewp,
                                               const float* __restrict__ ewd,
                                               const float* __restrict__ den_p,
                                               const float* __restrict__ den_d,
                                               const int* __restrict__ csr_off,
                                               const int* __restrict__ sorted_src,
                                               unsigned* __restrict__ gat_cat) {
    const int b = blockIdx.x;
    const int logical = (b & 7) * 3125 + (b >> 3);   // XCD-aware swizzle
    const int v = logical * 4 + (threadIdx.x >> 6);
    if (v >= N_NODES) return;
    const int lane = threadIdx.x & 63;
    const int head = (lane & 31) >> 3;   // channel-pair group -> head

    const int beg = __builtin_amdgcn_readfirstlane(csr_off[v]);
    const int end = __builtin_amdgcn_readfirstlane(csr_off[v + 1]);

    const float* __restrict__ wplane = (lane >= 32 ? ewd : ewp) + (size_t)head * N_EDGES;

    float2 a0 = {0,0}, a1 = {0,0}, a2 = {0,0}, a3 = {0,0};
    int e = beg;
    for (; e + 8 <= end; e += 8) {
        int4 s4a = *reinterpret_cast<const int4*>(sorted_src + e);
        int4 s4b = *reinterpret_cast<const int4*>(sorted_src + e + 4);
        const unsigned* b0 = hl + ((size_t)(unsigned)__builtin_amdgcn_readfirstlane(s4a.x) << 6);
        const unsigned* b1 = hl + ((size_t)(unsigned)__builtin_amdgcn_readfirstlane(s4a.y) << 6);
        const unsigned* b2 = hl + ((size_t)(unsigned)__builtin_amdgcn_readfirstlane(s4a.z) << 6);
        const unsigned* b3 = hl + ((size_t)(unsigned)__builtin_amdgcn_readfirstlane(s4a.w) << 6);
        const unsigned* b4 = hl + ((size_t)(unsigned)__builtin_amdgcn_readfirstlane(s4b.x) << 6);
        const unsigned* b5 = hl + ((size_t)(unsigned)__builtin_amdgcn_readfirstlane(s4b.y) << 6);
        const unsigned* b6 = hl + ((size_t)(unsigned)__builtin_amdgcn_readfirstlane(s4b.z) << 6);
        const unsigned* b7 = hl + ((size_t)(unsigned)__builtin_amdgcn_readfirstlane(s4b.w) << 6);
        float4 wa = *reinterpret_cast<const float4*>(wplane + e);
        float4 wb = *reinterpret_cast<const float4*>(wplane + e + 4);
        unsigned u0 = b0[lane], u1 = b1[lane], u2 = b2[lane], u3 = b3[lane];
        unsigned u4 = b4[lane], u5 = b5[lane], u6 = b6[lane], u7 = b7[lane];
        a0.x = fmaf(wa.x, bf_lo(u0), a0.x); a0.y = fmaf(wa.x, bf_hi(u0), a0.y);
        a1.x = fmaf(wa.y, bf_lo(u1), a1.x); a1.y = fmaf(wa.y, bf_hi(u1), a1.y);
        a2.x = fmaf(wa.z, bf_lo(u2), a2.x); a2.y = fmaf(wa.z, bf_hi(u2), a2.y);
        a3.x = fmaf(wa.w, bf_lo(u3), a3.x); a3.y = fmaf(wa.w, bf_hi(u3), a3.y);
        a0.x = fmaf(wb.x, bf_lo(u4), a0.x); a0.y = fmaf(wb.x, bf_hi(u4), a0.y);
        a1.x = fmaf(wb.y, bf_lo(u5), a1.x); a1.y = fmaf(wb.y, bf_hi(u5), a1.y);
        a2.x = fmaf(wb.z, bf_lo(u6), a2.x); a2.y = fmaf(wb.z, bf_hi(u6), a2.y);
        a3.x = fmaf(wb.w, bf_lo(u7), a3.x); a3.y = fmaf(wb.w, bf_hi(u7), a3.y);
    }
    for (; e + 4 <= end; e += 4) {
        int4 s4 = *reinterpret_cast<const int4*>(sorted_src + e);
        const unsigned* b0 = hl + ((size_t)(unsigned)__builtin_amdgcn_readfirstlane(s4.x) << 6);
        const unsigned* b1 = hl + ((size_t)(unsigned)__builtin_amdgcn_readfirstlane(s4.y) << 6);
        const unsigned* b2 = hl + ((size_t)(unsigned)__builtin_amdgcn_readfirstlane(s4.z) << 6);
        const unsigned* b3 = hl + ((size_t)(unsigned)__builtin_amdgcn_readfirstlane(s4.w) << 6);
        float4 wa = *reinterpret_cast<const float4*>(wplane + e);
        unsigned u0 = b0[lane], u1 = b1[lane], u2 = b2[lane], u3 = b3[lane];
        a0.x = fmaf(wa.x, bf_lo(u0), a0.x); a0.y = fmaf(wa.x, bf_hi(u0), a0.y);
        a1.x = fmaf(wa.y, bf_lo(u1), a1.x); a1.y = fmaf(wa.y, bf_hi(u1), a1.y);
        a2.x = fmaf(wa.z, bf_lo(u2), a2.x); a2.y = fmaf(wa.z, bf_hi(u2), a2.y);
        a3.x = fmaf(wa.w, bf_lo(u3), a3.x); a3.y = fmaf(wa.w, bf_hi(u3), a3.y);
    }
    float2 acc = {(a0.x + a1.x) + (a2.x + a3.x), (a0.y + a1.y) + (a2.y + a3.y)};
    for (; e < end; ++e) {
        const unsigned* b0 = hl + ((size_t)(unsigned)__builtin_amdgcn_readfirstlane(sorted_src[e]) << 6);
        float wv = wplane[e];
        unsigned u0 = b0[lane];
        acc.x = fmaf(wv, bf_lo(u0), acc.x);
        acc.y = fmaf(wv, bf_hi(u0), acc.y);
    }
    const float den = (lane >= 32 ? den_d : den_p)[v * 4 + head] + 1e-16f;
    gat_cat[(size_t)v * 64 + lane] = bf_pack(acc.x / den, acc.y / den);
}

// ---------------- BN + ELU + fused graph pooling (optional F write-back) ----------------
template <bool WRITEF>
__global__ __launch_bounds__(256) void bn_elu(float* __restrict__ F, const float* __restrict__ stats,
                                              const float* __restrict__ gamma, const float* __restrict__ beta,
                                              float* __restrict__ pooled) {
    __shared__ float red[256];
    const int t = threadIdx.x;
    const int idx = blockIdx.x * 256 + t;
    const int c = t & 63;
    float mu = stats[c] * (1.0f / (float)N_NODES);
    float var = stats[64 + c] * (1.0f / (float)N_NODES) - mu * mu;
    float inv = rsqrtf(var + BN_EPS);
    float v = (F[idx] - mu) * inv * gamma[c] + beta[c];
    v = (v > 0.f) ? v : expm1f(v);
    if (WRITEF) F[idx] = v;
    red[t] = v;
    __syncthreads();
    if (t < 64) {
        float s = red[c] + red[64 + c] + red[128 + c] + red[192 + c];
        int g = (blockIdx.x * 4) / NPG;    // all 4 nodes in same graph
        atomicAdd(&pooled[g * 64 + c], s);
    }
}

// ---------------- task head: one wave per graph, residual folded in via pooled F0 ----------------
__global__ __launch_bounds__(64) void task_head(const float* __restrict__ pooled,
                                                const float* __restrict__ pooledF0,
                                                const float* __restrict__ resW,
                                                const float* __restrict__ resb,
                                                const float* __restrict__ taskW,
                                                const float* __restrict__ taskb,
                                                float* __restrict__ out) {
    const int g = blockIdx.x;
    const int c = threadIdx.x;
    float rc = 0.f;
    const float* pf = pooledF0 + g * 64;
    for (int k = 0; k < 64; ++k)
        rc = fmaf(pf[k], resW[k * 64 + c], rc);
    float p = (pooled[g * 64 + c] + rc) * (1.0f / (float)NPG) + resb[c];
#pragma unroll
    for (int o = 0; o < OUT_DIM; ++o) {
        float partial = p * taskW[c * OUT_DIM + o];
#pragma unroll
        for (int m = 1; m < 64; m <<= 1) partial += __shfl_xor(partial, m);
        if (c == 0) out[g * OUT_DIM + o] = partial + taskb[o];
    }
}

// ---------------- head-diversity loss for both layers ----------------
__global__ __launch_bounds__(256) void div_loss(const float* __restrict__ dW0,
                                                const float* __restrict__ dW1,
                                                float* __restrict__ out) {
    __shared__ float red[16][16];
    float total = 0.f;
    for (int layer = 0; layer < 2; ++layer) {
        const float* W = layer ? dW1 : dW0;
        const int din = layer ? 64 : 80;
        const int p = threadIdx.x & 15;
        const int s16 = threadIdx.x >> 4;
        const int i = p >> 2, j = p & 3;
        float acc = 0.f;
        const int Kk = din * 16;
        for (int kk = s16; kk < Kk; kk += 16) {
            int rrow = kk >> 4, cc = kk & 15;
            acc += W[rrow * 64 + i * 16 + cc] * W[rrow * 64 + j * 16 + cc];
        }
        red[p][s16] = acc;
        __syncthreads();
        if (threadIdx.x < 16) {
            float s = 0.f;
            for (int m = 0; m < 16; ++m) s += red[threadIdx.x][m];
            red[threadIdx.x][0] = s;
        }
        __syncthreads();
        if (threadIdx.x == 0) {
            float G[4][4], nrm[4];
            for (int a = 0; a < 4; ++a)
                for (int b = 0; b < 4; ++b) G[a][b] = red[a * 4 + b][0];
            for (int a = 0; a < 4; ++a) nrm[a] = sqrtf(G[a][a]) + 1e-12f;
            float l = 0.f;
            for (int a = 0; a < 4; ++a)
                for (int b = 0; b < 4; ++b) {
                    float gn = G[a][b] / (nrm[a] * nrm[b]);
                    float off = gn - (a == b ? 1.f : 0.f);
                    l += off * off;
                }
            total += 0.1f * l / 12.f;
        }
        __syncthreads();
    }
    if (threadIdx.x == 0) *out = total;
}

// ---------------- launcher ----------------
extern "C" void kernel_launch(void* const* d_in, const int* in_sizes, int n_in,
                              void* d_out, int out_size, void* d_ws, size_t ws_size,
                              hipStream_t stream) {
    const float* x      = (const float*)d_in[0];
    const int*   ei     = (const int*)d_in[1];
    const float* peW    = (const float*)d_in[3];
    const float* peb    = (const float*)d_in[4];

    const float* l_pW[2]   = {(const float*)d_in[5],  (const float*)d_in[17]};
    const float* l_pas[2]  = {(const float*)d_in[6],  (const float*)d_in[18]};
    const float* l_pad[2]  = {(const float*)d_in[7],  (const float*)d_in[19]};
    const float* l_posW[2] = {(const float*)d_in[8],  (const float*)d_in[20]};
    const float* l_posb[2] = {(const float*)d_in[9],  (const float*)d_in[21]};
    const float* l_dW[2]   = {(const float*)d_in[10], (const float*)d_in[22]};
    const float* l_das[2]  = {(const float*)d_in[11], (const float*)d_in[23]};
    const float* l_dad[2]  = {(const float*)d_in[12], (const float*)d_in[24]};
    const float* l_fW[2]   = {(const float*)d_in[13], (const float*)d_in[25]};
    const float* l_fb[2]   = {(const float*)d_in[14], (const float*)d_in[26]};
    const float* l_g[2]    = {(const float*)d_in[15], (const float*)d_in[27]};
    const float* l_b[2]    = {(const float*)d_in[16], (const float*)d_in[28]};
    const float* res_W  = (const float*)d_in[29];
    const float* res_b  = (const float*)d_in[30];
    const float* task_W = (const float*)d_in[31];
    const float* task_b = (const float*)d_in[32];

    float* ws = (float*)d_ws;
    float* ewp     = ws + OFF_EWP;
    float* pe_ws   = ws + OFF_PEWS;
    float* pooled  = ws + OFF_POOL;            // [100][64]
    float* pooledF0= ws + OFF_POOL + 6400;     // [100][64]
    float* den_p   = ws + OFF_DENP;
    float* den_d   = ws + OFF_DEND;
    unsigned* hl   = (unsigned*)(ws + OFF_HL);    // bf16 [N][128] = [N][64] uints
    unsigned* cat_bf = (unsigned*)(ws + OFF_CAT); // bf16 [N][128] = [N][64] uints
    float* F0      = ws + OFF_F0;
    float* F1      = ws + OFF_F1;
    float* ewd     = ws + OFF_EWD;   // aliases F1
    float2* sps    = (float2*)(ws + OFF_SPS);
    float2* dpd    = (float2*)(ws + OFF_DPD);
    float* stats   = ws + OFF_STATS;
    int*   csr_off    = (int*)(ws + OFF_CSR);
    int*   sorted_src = (int*)(ws + OFF_SRT);
    float* out = (float*)d_out;

    const int NODE_BLOCKS = (N_NODES + 3) / 4;      // 25000
    const int GEMM_BLOCKS = (N_NODES + 63) / 64;    // 1563
    const int BN_BLOCKS   = N_NODES * 64 / 256;     // 25000

    sort_edges<<<N_GRAPHS, 1024, 0, stream>>>(ei, csr_off, sorted_src);
    prep_pe<<<1, 256, 0, stream>>>(peW, peb, l_pW[0], l_dW[0], pe_ws);
    hipMemsetAsync(pooled, 0, 2 * N_GRAPHS * 64 * sizeof(float), stream);  // pooled + pooledF0

    // ----- layer 0 -----
    gemm_dual_rt<true><<<GEMM_BLOCKS, 256, 0, stream>>>(x, l_pW[0], l_dW[0], pe_ws,
        l_pas[0], l_pad[0], l_das[0], l_dad[0],
        hl, sps, dpd);
    edge_weights<<<NODE_BLOCKS, 256, 0, stream>>>(sps, dpd,
        csr_off, sorted_src, l_posW[0], l_posb[0], ewp, ewd, den_p, den_d);
    gat_agg<<<NODE_BLOCKS, 256, 0, stream>>>(hl, ewp, ewd, den_p, den_d,
        csr_off, sorted_src, cat_bf);
    hipMemsetAsync(stats, 0, 128 * sizeof(float), stream);
    gemm_rt_bf<<<GEMM_BLOCKS, 256, 0, stream>>>(cat_bf, l_fW[0], l_fb[0], F0, stats);
    bn_elu<true><<<BN_BLOCKS, 256, 0, stream>>>(F0, stats, l_g[0], l_b[0], pooledF0);

    // ----- layer 1 -----
    gemm_dual_rt<false><<<GEMM_BLOCKS, 256, 0, stream>>>(F0, l_pW[1], l_dW[1], pe_ws,
        l_pas[1], l_pad[1], l_das[1], l_dad[1],
        hl, sps, dpd);
    edge_weights<<<NODE_BLOCKS, 256, 0, stream>>>(sps, dpd,
        csr_off, sorted_src, l_posW[1], l_posb[1], ewp, ewd, den_p, den_d);
    gat_agg<<<NODE_BLOCKS, 256, 0, stream>>>(hl, ewp, ewd, den_p, den_d,
        csr_off, sorted_src, cat_bf);
    hipMemsetAsync(stats, 0, 128 * sizeof(float), stream);
    gemm_rt_bf<<<GEMM_BLOCKS, 256, 0, stream>>>(cat_bf, l_fW[1], l_fb[1], F1, stats);
    bn_elu<false><<<BN_BLOCKS, 256, 0, stream>>>(F1, stats, l_g[1], l_b[1], pooled);

    // ----- task head (residual folded via pooled F0) + diversity loss -----
    task_head<<<N_GRAPHS, 64, 0, stream>>>(pooled, pooledF0, res_W, res_b,
                                           task_W, task_b, out);
    div_loss<<<1, 256, 0, stream>>>(l_dW[0], l_dW[1], out + 1000);
}